// Round 15
// baseline (1959.851 us; speedup 1.0000x reference)
//
#include <hip/hip_runtime.h>

typedef __attribute__((ext_vector_type(4))) float f32x4;
typedef __attribute__((ext_vector_type(8))) short bf16x8;

__device__ __forceinline__ unsigned short f2bf(float f){
  unsigned int x = __float_as_uint(f);
  return (unsigned short)((x + 0x7fffu + ((x >> 16) & 1u)) >> 16); // RNE
}

// ---------------- SE3 via explicit rotation matrices (fp32, exact) ----------------
struct Q  { float w,x,y,z; };
struct V3 { float x,y,z; };
struct M3 { float m[9]; };

__device__ __forceinline__ Q qmul(Q a, Q b){
  return { a.w*b.w - a.x*b.x - a.y*b.y - a.z*b.z,
           a.w*b.x + a.x*b.w + a.y*b.z - a.z*b.y,
           a.w*b.y - a.x*b.z + a.y*b.w + a.z*b.x,
           a.w*b.z + a.x*b.y - a.y*b.x + a.z*b.w };
}
__device__ __forceinline__ Q qconj(Q q){ return { q.w, -q.x, -q.y, -q.z }; }
__device__ __forceinline__ M3 q2R(Q q){
  const float w=q.w, x=q.x, y=q.y, z=q.z;
  M3 R;
  R.m[0]=1.f-2.f*(y*y+z*z); R.m[1]=2.f*(x*y-w*z);     R.m[2]=2.f*(x*z+w*y);
  R.m[3]=2.f*(x*y+w*z);     R.m[4]=1.f-2.f*(x*x+z*z); R.m[5]=2.f*(y*z-w*x);
  R.m[6]=2.f*(x*z-w*y);     R.m[7]=2.f*(y*z+w*x);     R.m[8]=1.f-2.f*(x*x+y*y);
  return R;
}
__device__ __forceinline__ V3 mv (M3 R, V3 v){
  return { R.m[0]*v.x + R.m[1]*v.y + R.m[2]*v.z,
           R.m[3]*v.x + R.m[4]*v.y + R.m[5]*v.z,
           R.m[6]*v.x + R.m[7]*v.y + R.m[8]*v.z };
}
__device__ __forceinline__ V3 mtv(M3 R, V3 v){
  return { R.m[0]*v.x + R.m[3]*v.y + R.m[6]*v.z,
           R.m[1]*v.x + R.m[4]*v.y + R.m[7]*v.z,
           R.m[2]*v.x + R.m[5]*v.y + R.m[8]*v.z };
}

// ---------------- single kernel: 128 edges/block, 4 waves (32 cols x 128 edges each) ----
// Green-proven paths only: A via LDS bf16 slabs, B in-flight per-lane scalar fp32->bf16,
// fp32 ef residual from global (tight L2-hot gap), no d_ws.
// Slab order (ef last): 0=xfi(k0=0) 1=xfj(k0=128) 2=tail128(k0=384) 3=tail32(k0=512) 4=ef(k0=256)
__global__ __launch_bounds__(256, 2) void edge_k(
    const float* __restrict__ xfi, const float* __restrict__ xfj, const float* __restrict__ ef,
    const float* __restrict__ Ti,  const float* __restrict__ Tj,  const float* __restrict__ Th,
    const int*   __restrict__ batch, const float* __restrict__ u,
    const float* __restrict__ W1,  const float* __restrict__ b1,
    const float* __restrict__ W2,  const float* __restrict__ b2,
    float* __restrict__ outE, float* __restrict__ outT, int E)
{
  __shared__ __align__(16) unsigned short fbuf[128][136]; // slab buffer, then h
  __shared__ float terr_s[128][8];
  __shared__ int   ibat_s[128];

  const int tid = threadIdx.x;              // 0..255 (4 waves)
  const long base = (long)blockIdx.x * 128;

  // ---- Phase 1: SE3 error, threads 0..127 (one edge each) + Tij_hat passthrough ----
  if (tid < 128){
    const long row = base + tid;
    const long rc  = row < E ? row : (long)(E-1);
    const float* pi = Ti + rc*7;
    const float* pj = Tj + rc*7;
    const float* ph = Th + rc*7;
    Q  qi{pi[0],pi[1],pi[2],pi[3]};  V3 tti{pi[4],pi[5],pi[6]};
    Q  qj{pj[0],pj[1],pj[2],pj[3]};  V3 ttj{pj[4],pj[5],pj[6]};
    Q  qh{ph[0],ph[1],ph[2],ph[3]};  V3 tth{ph[4],ph[5],ph[6]};
    M3 Ri = q2R(qi), Rj = q2R(qj), Rh = q2R(qh);
    V3 a  = mtv(Rj, ttj);
    V3 bv = mv(Ri, a);
    V3 c  { tti.x - bv.x, tti.y - bv.y, tti.z - bv.z };
    V3 d  = mv(Rh, c);
    Q  qe = qmul(qmul(qh, qi), qconj(qj));
    terr_s[tid][0] = qe.w;  terr_s[tid][1] = qe.x;
    terr_s[tid][2] = qe.y;  terr_s[tid][3] = qe.z;
    terr_s[tid][4] = tth.x + d.x;
    terr_s[tid][5] = tth.y + d.y;
    terr_s[tid][6] = tth.z + d.z;
    terr_s[tid][7] = 0.f;
    ibat_s[tid] = batch[rc];
    if (row < E){
      float* o = outT + row*7;
      o[0]=ph[0]; o[1]=ph[1]; o[2]=ph[2]; o[3]=ph[3];
      o[4]=ph[4]; o[5]=ph[5]; o[6]=ph[6];
    }
  }

  const int lane = tid & 63, wv = tid >> 6;   // 4 waves, wave owns cols [32wv, 32wv+32)
  const int l15 = lane & 15, l4 = lane >> 4;

  // ---- GEMM1 accumulators: 8 A-groups x 2 col-fragments ----
  f32x4 acc1[8][2];
  #pragma unroll
  for (int cf = 0; cf < 2; ++cf){
    const int col = wv*32 + cf*16 + l15;
    const float bv = b1[col];
    #pragma unroll
    for (int a = 0; a < 8; ++a){
      #pragma unroll
      for (int r = 0; r < 4; ++r) acc1[a][cf][r] = bv;
    }
  }
  f32x4 acc2[8][2];

  const int   kbase[5]  = { 0, 128, 384, 512, 256 };
  const int   nchunk[5] = { 4, 4, 4, 1, 4 };

  for (int s = 0; s < 5; ++s){
    __syncthreads();                          // previous slab consumed / phase-1 ready
    // ---- stage slab s into fbuf ----
    if (s == 0 || s == 1 || s == 4){
      const float* F = (s == 0) ? xfi : (s == 1) ? xfj : ef;
      #pragma unroll
      for (int i = 0; i < 16; ++i){           // 128x32 float4 / 256 thr
        const int idx = i*256 + tid;
        const int e = idx >> 5, c4 = (idx & 31) << 2;
        long rr = base + e; if (rr >= E) rr = E-1;
        const float4 v = *reinterpret_cast<const float4*>(F + (size_t)rr*128 + c4);
        unsigned short* dst = &fbuf[e][c4];
        dst[0]=f2bf(v.x); dst[1]=f2bf(v.y); dst[2]=f2bf(v.z); dst[3]=f2bf(v.w);
      }
    } else if (s == 2){
      #pragma unroll
      for (int i = 0; i < 64; ++i){           // 128x128 / 256 thr
        const int idx = i*256 + tid;
        const int e = idx >> 7, c = idx & 127;
        const float v = (c < 7) ? terr_s[e][c] : u[(size_t)ibat_s[e]*128 + (c-7)];
        fbuf[e][c] = f2bf(v);
      }
    } else { // s == 3: k = 512..543 -> u[121..127] then zeros
      #pragma unroll
      for (int i = 0; i < 16; ++i){           // 128x32 / 256 thr
        const int idx = i*256 + tid;
        const int e = idx >> 5, c = idx & 31;
        const float v = (c < 7) ? u[(size_t)ibat_s[e]*128 + 121 + c] : 0.f;
        fbuf[e][c] = f2bf(v);
      }
    }
    __syncthreads();

    // ---- acc2 init right after ef slab staged (tight L2-hot re-read, fp32) ----
    if (s == 4){
      #pragma unroll
      for (int cf = 0; cf < 2; ++cf){
        const int col = wv*32 + cf*16 + l15;
        const float bv2 = b2[col];
        #pragma unroll
        for (int a = 0; a < 8; ++a){
          #pragma unroll
          for (int r = 0; r < 4; ++r){
            long orow = base + a*16 + l4*4 + r;
            if (orow >= E) orow = E-1;
            acc2[a][cf][r] = ef[(size_t)orow*128 + col] + bv2;
          }
        }
      }
    }

    // ---- MFMA chunks of this slab (B in-flight from fp32 W1, green pattern) ----
    for (int kc = 0; kc < nchunk[s]; ++kc){
      const int kl = kc*32 + l4*8;
      bf16x8 afr[8];
      #pragma unroll
      for (int a = 0; a < 8; ++a)
        afr[a] = *reinterpret_cast<const bf16x8*>(&fbuf[a*16 + l15][kl]);
      #pragma unroll
      for (int cf = 0; cf < 2; ++cf){
        const int col = wv*32 + cf*16 + l15;
        union { bf16x8 v; unsigned short us[8]; } B;
        #pragma unroll
        for (int j = 0; j < 8; ++j){
          const int kk = kbase[s] + kc*32 + l4*8 + j;
          B.us[j] = (kk < 519) ? f2bf(W1[(size_t)kk*128 + col]) : (unsigned short)0;
        }
        #pragma unroll
        for (int a = 0; a < 8; ++a)
          acc1[a][cf] = __builtin_amdgcn_mfma_f32_16x16x32_bf16(afr[a], B.v, acc1[a][cf], 0, 0, 0);
      }
    }
  }
  __syncthreads();   // ef slab consumed; fbuf free for h

  // ---- h = relu -> bf16 into fbuf; C/D: col=32wv+16cf+l15, edge=a*16+l4*4+r ----
  #pragma unroll
  for (int a = 0; a < 8; ++a){
    #pragma unroll
    for (int cf = 0; cf < 2; ++cf){
      const int col = wv*32 + cf*16 + l15;
      #pragma unroll
      for (int r = 0; r < 4; ++r)
        fbuf[a*16 + l4*4 + r][col] = f2bf(fmaxf(acc1[a][cf][r], 0.f));
    }
  }
  __syncthreads();

  // ---- GEMM2: acc2 += h @ W2 (A from LDS, B in-flight) ----
  #pragma unroll
  for (int ks = 0; ks < 4; ++ks){
    const int k0 = ks*32 + l4*8;
    bf16x8 afr[8];
    #pragma unroll
    for (int a = 0; a < 8; ++a)
      afr[a] = *reinterpret_cast<const bf16x8*>(&fbuf[a*16 + l15][k0]);
    #pragma unroll
    for (int cf = 0; cf < 2; ++cf){
      const int col = wv*32 + cf*16 + l15;
      union { bf16x8 v; unsigned short us[8]; } B;
      #pragma unroll
      for (int j = 0; j < 8; ++j)
        B.us[j] = f2bf(W2[(size_t)(k0 + j)*128 + col]);
      #pragma unroll
      for (int a = 0; a < 8; ++a)
        acc2[a][cf] = __builtin_amdgcn_mfma_f32_16x16x32_bf16(afr[a], B.v, acc2[a][cf], 0, 0, 0);
    }
  }

  // ---- store edge_feat_out ----
  #pragma unroll
  for (int a = 0; a < 8; ++a){
    #pragma unroll
    for (int cf = 0; cf < 2; ++cf){
      const int col = wv*32 + cf*16 + l15;
      #pragma unroll
      for (int r = 0; r < 4; ++r){
        const long orow = base + a*16 + l4*4 + r;
        if (orow < E) outE[(size_t)orow*128 + col] = acc2[a][cf][r];
      }
    }
  }
}

extern "C" void kernel_launch(void* const* d_in, const int* in_sizes, int n_in,
                              void* d_out, int out_size, void* d_ws, size_t ws_size,
                              hipStream_t stream){
  const float* xfi  = (const float*)d_in[0];
  const float* xfj  = (const float*)d_in[1];
  const float* ef   = (const float*)d_in[2];
  const float* Ti   = (const float*)d_in[3];
  const float* Tj   = (const float*)d_in[4];
  const float* Th   = (const float*)d_in[5];
  const float* u    = (const float*)d_in[6];
  const int*   bat  = (const int*)d_in[7];
  const float* W1   = (const float*)d_in[8];
  const float* b1   = (const float*)d_in[9];
  const float* W2   = (const float*)d_in[10];
  const float* b2   = (const float*)d_in[11];
  const int E = in_sizes[0] / 128;

  float* outE = (float*)d_out;
  float* outT = outE + (size_t)E * 128;

  (void)d_ws; (void)ws_size;
  edge_k<<<(E + 127)/128, 256, 0, stream>>>(xfi, xfj, ef, Ti, Tj, Th, bat, u,
                                            W1, b1, W2, b2, outE, outT, E);
}

// Round 16
// 1452.275 us; speedup vs baseline: 1.3495x; 1.3495x over previous
//
#include <hip/hip_runtime.h>

typedef __attribute__((ext_vector_type(4))) float f32x4;
typedef __attribute__((ext_vector_type(8))) short bf16x8;

__device__ __forceinline__ unsigned short f2bf(float f){
  unsigned int x = __float_as_uint(f);
  return (unsigned short)((x + 0x7fffu + ((x >> 16) & 1u)) >> 16); // RNE
}

// ---------------- SE3 via explicit rotation matrices (fp32, exact) ----------------
struct Q  { float w,x,y,z; };
struct V3 { float x,y,z; };
struct M3 { float m[9]; };

__device__ __forceinline__ Q qmul(Q a, Q b){
  return { a.w*b.w - a.x*b.x - a.y*b.y - a.z*b.z,
           a.w*b.x + a.x*b.w + a.y*b.z - a.z*b.y,
           a.w*b.y - a.x*b.z + a.y*b.w + a.z*b.x,
           a.w*b.z + a.x*b.y - a.y*b.x + a.z*b.w };
}
__device__ __forceinline__ Q qconj(Q q){ return { q.w, -q.x, -q.y, -q.z }; }
__device__ __forceinline__ M3 q2R(Q q){
  const float w=q.w, x=q.x, y=q.y, z=q.z;
  M3 R;
  R.m[0]=1.f-2.f*(y*y+z*z); R.m[1]=2.f*(x*y-w*z);     R.m[2]=2.f*(x*z+w*y);
  R.m[3]=2.f*(x*y+w*z);     R.m[4]=1.f-2.f*(x*x+z*z); R.m[5]=2.f*(y*z-w*x);
  R.m[6]=2.f*(x*z-w*y);     R.m[7]=2.f*(y*z+w*x);     R.m[8]=1.f-2.f*(x*x+y*y);
  return R;
}
__device__ __forceinline__ V3 mv (M3 R, V3 v){
  return { R.m[0]*v.x + R.m[1]*v.y + R.m[2]*v.z,
           R.m[3]*v.x + R.m[4]*v.y + R.m[5]*v.z,
           R.m[6]*v.x + R.m[7]*v.y + R.m[8]*v.z };
}
__device__ __forceinline__ V3 mtv(M3 R, V3 v){
  return { R.m[0]*v.x + R.m[3]*v.y + R.m[6]*v.z,
           R.m[1]*v.x + R.m[4]*v.y + R.m[7]*v.z,
           R.m[2]*v.x + R.m[5]*v.y + R.m[8]*v.z };
}

// ---------------- single kernel: 128 edges/block, 8 waves (16 cols x 128 edges each) ----
// Green-proven paths: A via LDS bf16 slabs, B in-flight per-lane scalar fp32->bf16,
// fp32 ef residual from global in the tight post-ef-stage L2 window, no d_ws.
// Slab order (ef last): 0=xfi(k0=0) 1=xfj(k0=128) 2=tail128(k0=384) 3=tail32(k0=512) 4=ef(k0=256)
__global__ __launch_bounds__(512, 4) void edge_k(
    const float* __restrict__ xfi, const float* __restrict__ xfj, const float* __restrict__ ef,
    const float* __restrict__ Ti,  const float* __restrict__ Tj,  const float* __restrict__ Th,
    const int*   __restrict__ batch, const float* __restrict__ u,
    const float* __restrict__ W1,  const float* __restrict__ b1,
    const float* __restrict__ W2,  const float* __restrict__ b2,
    float* __restrict__ outE, float* __restrict__ outT, int E)
{
  __shared__ __align__(16) unsigned short fbuf[128][136]; // slab buffer, then h
  __shared__ float terr_s[128][8];
  __shared__ int   ibat_s[128];

  const int tid = threadIdx.x;              // 0..511 (8 waves)
  const long base = (long)blockIdx.x * 128;

  // ---- Phase 1: SE3 error, threads 0..127 (one edge each) + Tij_hat passthrough ----
  if (tid < 128){
    const long row = base + tid;
    const long rc  = row < E ? row : (long)(E-1);
    const float* pi = Ti + rc*7;
    const float* pj = Tj + rc*7;
    const float* ph = Th + rc*7;
    Q  qi{pi[0],pi[1],pi[2],pi[3]};  V3 tti{pi[4],pi[5],pi[6]};
    Q  qj{pj[0],pj[1],pj[2],pj[3]};  V3 ttj{pj[4],pj[5],pj[6]};
    Q  qh{ph[0],ph[1],ph[2],ph[3]};  V3 tth{ph[4],ph[5],ph[6]};
    M3 Ri = q2R(qi), Rj = q2R(qj), Rh = q2R(qh);
    V3 a  = mtv(Rj, ttj);
    V3 bv = mv(Ri, a);
    V3 c  { tti.x - bv.x, tti.y - bv.y, tti.z - bv.z };
    V3 d  = mv(Rh, c);
    Q  qe = qmul(qmul(qh, qi), qconj(qj));
    terr_s[tid][0] = qe.w;  terr_s[tid][1] = qe.x;
    terr_s[tid][2] = qe.y;  terr_s[tid][3] = qe.z;
    terr_s[tid][4] = tth.x + d.x;
    terr_s[tid][5] = tth.y + d.y;
    terr_s[tid][6] = tth.z + d.z;
    terr_s[tid][7] = 0.f;
    ibat_s[tid] = batch[rc];
    if (row < E){
      float* o = outT + row*7;
      o[0]=ph[0]; o[1]=ph[1]; o[2]=ph[2]; o[3]=ph[3];
      o[4]=ph[4]; o[5]=ph[5]; o[6]=ph[6];
    }
  }

  const int lane = tid & 63, wv = tid >> 6;   // 8 waves; wave owns cols [16wv, 16wv+16)
  const int l15 = lane & 15, l4 = lane >> 4;
  const int col = wv*16 + l15;

  // ---- accumulators: 8 A-groups x 1 col-fragment each ----
  f32x4 acc1[8];
  {
    const float bv = b1[col];
    #pragma unroll
    for (int a = 0; a < 8; ++a){
      #pragma unroll
      for (int r = 0; r < 4; ++r) acc1[a][r] = bv;
    }
  }
  f32x4 acc2[8];

  const int kbase[5]  = { 0, 128, 384, 512, 256 };
  const int nchunk[5] = { 4, 4, 4, 1, 4 };

  for (int s = 0; s < 5; ++s){
    __syncthreads();                          // previous slab consumed / phase-1 ready
    // ---- stage slab s into fbuf ----
    if (s == 0 || s == 1 || s == 4){
      const float* F = (s == 0) ? xfi : (s == 1) ? xfj : ef;
      #pragma unroll
      for (int i = 0; i < 8; ++i){            // 128x32 float4 / 512 thr
        const int idx = i*512 + tid;
        const int e = idx >> 5, c4 = (idx & 31) << 2;
        long rr = base + e; if (rr >= E) rr = E-1;
        const float4 v = *reinterpret_cast<const float4*>(F + (size_t)rr*128 + c4);
        unsigned short* dst = &fbuf[e][c4];
        dst[0]=f2bf(v.x); dst[1]=f2bf(v.y); dst[2]=f2bf(v.z); dst[3]=f2bf(v.w);
      }
    } else if (s == 2){
      #pragma unroll
      for (int i = 0; i < 32; ++i){           // 128x128 / 512 thr
        const int idx = i*512 + tid;
        const int e = idx >> 7, c = idx & 127;
        const float v = (c < 7) ? terr_s[e][c] : u[(size_t)ibat_s[e]*128 + (c-7)];
        fbuf[e][c] = f2bf(v);
      }
    } else { // s == 3: k = 512..543 -> u[121..127] then zeros
      #pragma unroll
      for (int i = 0; i < 8; ++i){            // 128x32 / 512 thr
        const int idx = i*512 + tid;
        const int e = idx >> 5, c = idx & 31;
        const float v = (c < 7) ? u[(size_t)ibat_s[e]*128 + 121 + c] : 0.f;
        fbuf[e][c] = f2bf(v);
      }
    }
    __syncthreads();

    // ---- acc2 init right after ef slab staged (tight L2-hot re-read, fp32) ----
    if (s == 4){
      const float bv2 = b2[col];
      #pragma unroll
      for (int a = 0; a < 8; ++a){
        #pragma unroll
        for (int r = 0; r < 4; ++r){
          long orow = base + a*16 + l4*4 + r;
          if (orow >= E) orow = E-1;
          acc2[a][r] = ef[(size_t)orow*128 + col] + bv2;
        }
      }
    }

    // ---- MFMA chunks of this slab (B in-flight from fp32 W1, green pattern) ----
    for (int kc = 0; kc < nchunk[s]; ++kc){
      const int kl = kc*32 + l4*8;
      union { bf16x8 v; unsigned short us[8]; } B;
      #pragma unroll
      for (int j = 0; j < 8; ++j){
        const int kk = kbase[s] + kl + j;
        B.us[j] = (kk < 519) ? f2bf(W1[(size_t)kk*128 + col]) : (unsigned short)0;
      }
      #pragma unroll
      for (int a = 0; a < 8; ++a){
        const bf16x8 afr = *reinterpret_cast<const bf16x8*>(&fbuf[a*16 + l15][kl]);
        acc1[a] = __builtin_amdgcn_mfma_f32_16x16x32_bf16(afr, B.v, acc1[a], 0, 0, 0);
      }
    }
  }
  __syncthreads();   // ef slab consumed; fbuf free for h

  // ---- h = relu -> bf16 into fbuf; C/D: col, edge row = a*16 + l4*4 + r ----
  #pragma unroll
  for (int a = 0; a < 8; ++a){
    #pragma unroll
    for (int r = 0; r < 4; ++r)
      fbuf[a*16 + l4*4 + r][col] = f2bf(fmaxf(acc1[a][r], 0.f));
  }
  __syncthreads();

  // ---- GEMM2: acc2 += h @ W2 (A from LDS, B in-flight) ----
  #pragma unroll
  for (int ks = 0; ks < 4; ++ks){
    const int k0 = ks*32 + l4*8;
    union { bf16x8 v; unsigned short us[8]; } B;
    #pragma unroll
    for (int j = 0; j < 8; ++j)
      B.us[j] = f2bf(W2[(size_t)(k0 + j)*128 + col]);
    #pragma unroll
    for (int a = 0; a < 8; ++a){
      const bf16x8 afr = *reinterpret_cast<const bf16x8*>(&fbuf[a*16 + l15][k0]);
      acc2[a] = __builtin_amdgcn_mfma_f32_16x16x32_bf16(afr, B.v, acc2[a], 0, 0, 0);
    }
  }

  // ---- store edge_feat_out ----
  #pragma unroll
  for (int a = 0; a < 8; ++a){
    #pragma unroll
    for (int r = 0; r < 4; ++r){
      const long orow = base + a*16 + l4*4 + r;
      if (orow < E) outE[(size_t)orow*128 + col] = acc2[a][r];
    }
  }
}

extern "C" void kernel_launch(void* const* d_in, const int* in_sizes, int n_in,
                              void* d_out, int out_size, void* d_ws, size_t ws_size,
                              hipStream_t stream){
  const float* xfi  = (const float*)d_in[0];
  const float* xfj  = (const float*)d_in[1];
  const float* ef   = (const float*)d_in[2];
  const float* Ti   = (const float*)d_in[3];
  const float* Tj   = (const float*)d_in[4];
  const float* Th   = (const float*)d_in[5];
  const float* u    = (const float*)d_in[6];
  const int*   bat  = (const int*)d_in[7];
  const float* W1   = (const float*)d_in[8];
  const float* b1   = (const float*)d_in[9];
  const float* W2   = (const float*)d_in[10];
  const float* b2   = (const float*)d_in[11];
  const int E = in_sizes[0] / 128;

  float* outE = (float*)d_out;
  float* outT = outE + (size_t)E * 128;

  (void)d_ws; (void)ws_size;
  edge_k<<<(E + 127)/128, 512, 0, stream>>>(xfi, xfj, ef, Ti, Tj, Th, bat, u,
                                            W1, b1, W2, b2, outE, outT, E);
}

// Round 17
// 1398.514 us; speedup vs baseline: 1.4014x; 1.0384x over previous
//
#include <hip/hip_runtime.h>

typedef __attribute__((ext_vector_type(4))) float f32x4;
typedef __attribute__((ext_vector_type(8))) short bf16x8;

__device__ __forceinline__ unsigned short f2bf(float f){
  unsigned int x = __float_as_uint(f);
  return (unsigned short)((x + 0x7fffu + ((x >> 16) & 1u)) >> 16); // RNE
}

// ---------------- SE3 via explicit rotation matrices (fp32, exact) ----------------
struct Q  { float w,x,y,z; };
struct V3 { float x,y,z; };
struct M3 { float m[9]; };

__device__ __forceinline__ Q qmul(Q a, Q b){
  return { a.w*b.w - a.x*b.x - a.y*b.y - a.z*b.z,
           a.w*b.x + a.x*b.w + a.y*b.z - a.z*b.y,
           a.w*b.y - a.x*b.z + a.y*b.w + a.z*b.x,
           a.w*b.z + a.x*b.y - a.y*b.x + a.z*b.w };
}
__device__ __forceinline__ Q qconj(Q q){ return { q.w, -q.x, -q.y, -q.z }; }
__device__ __forceinline__ M3 q2R(Q q){
  const float w=q.w, x=q.x, y=q.y, z=q.z;
  M3 R;
  R.m[0]=1.f-2.f*(y*y+z*z); R.m[1]=2.f*(x*y-w*z);     R.m[2]=2.f*(x*z+w*y);
  R.m[3]=2.f*(x*y+w*z);     R.m[4]=1.f-2.f*(x*x+z*z); R.m[5]=2.f*(y*z-w*x);
  R.m[6]=2.f*(x*z-w*y);     R.m[7]=2.f*(y*z+w*x);     R.m[8]=1.f-2.f*(x*x+y*y);
  return R;
}
__device__ __forceinline__ V3 mv (M3 R, V3 v){
  return { R.m[0]*v.x + R.m[1]*v.y + R.m[2]*v.z,
           R.m[3]*v.x + R.m[4]*v.y + R.m[5]*v.z,
           R.m[6]*v.x + R.m[7]*v.y + R.m[8]*v.z };
}
__device__ __forceinline__ V3 mtv(M3 R, V3 v){
  return { R.m[0]*v.x + R.m[3]*v.y + R.m[6]*v.z,
           R.m[1]*v.x + R.m[4]*v.y + R.m[7]*v.z,
           R.m[2]*v.x + R.m[5]*v.y + R.m[8]*v.z };
}

// ---------------- single kernel: 128 edges/block, 8 waves (16 cols x 128 edges each) ----
// Green-proven paths: A via LDS bf16 slabs, B in-flight per-lane scalar fp32->bf16,
// fp32 ef residual from global in the tight post-ef-stage L2 window, no d_ws.
// Slab order (ef last): 0=xfi(k0=0) 1=xfj(k0=128) 2=tail128(k0=384) 3=tail32(k0=512) 4=ef(k0=256)
__global__ __launch_bounds__(512) void edge_k(
    const float* __restrict__ xfi, const float* __restrict__ xfj, const float* __restrict__ ef,
    const float* __restrict__ Ti,  const float* __restrict__ Tj,  const float* __restrict__ Th,
    const int*   __restrict__ batch, const float* __restrict__ u,
    const float* __restrict__ W1,  const float* __restrict__ b1,
    const float* __restrict__ W2,  const float* __restrict__ b2,
    float* __restrict__ outE, float* __restrict__ outT, int E)
{
  __shared__ __align__(16) unsigned short fbuf[128][136]; // slab buffer, then h
  __shared__ float terr_s[128][8];
  __shared__ int   ibat_s[128];

  const int tid = threadIdx.x;              // 0..511 (8 waves)
  const long base = (long)blockIdx.x * 128;

  // ---- Phase 1: SE3 error, threads 0..127 (one edge each) + Tij_hat passthrough ----
  if (tid < 128){
    const long row = base + tid;
    const long rc  = row < E ? row : (long)(E-1);
    const float* pi = Ti + rc*7;
    const float* pj = Tj + rc*7;
    const float* ph = Th + rc*7;
    Q  qi{pi[0],pi[1],pi[2],pi[3]};  V3 tti{pi[4],pi[5],pi[6]};
    Q  qj{pj[0],pj[1],pj[2],pj[3]};  V3 ttj{pj[4],pj[5],pj[6]};
    Q  qh{ph[0],ph[1],ph[2],ph[3]};  V3 tth{ph[4],ph[5],ph[6]};
    M3 Ri = q2R(qi), Rj = q2R(qj), Rh = q2R(qh);
    V3 a  = mtv(Rj, ttj);
    V3 bv = mv(Ri, a);
    V3 c  { tti.x - bv.x, tti.y - bv.y, tti.z - bv.z };
    V3 d  = mv(Rh, c);
    Q  qe = qmul(qmul(qh, qi), qconj(qj));
    terr_s[tid][0] = qe.w;  terr_s[tid][1] = qe.x;
    terr_s[tid][2] = qe.y;  terr_s[tid][3] = qe.z;
    terr_s[tid][4] = tth.x + d.x;
    terr_s[tid][5] = tth.y + d.y;
    terr_s[tid][6] = tth.z + d.z;
    terr_s[tid][7] = 0.f;
    ibat_s[tid] = batch[rc];
    if (row < E){
      float* o = outT + row*7;
      o[0]=ph[0]; o[1]=ph[1]; o[2]=ph[2]; o[3]=ph[3];
      o[4]=ph[4]; o[5]=ph[5]; o[6]=ph[6];
    }
  }

  const int lane = tid & 63, wv = tid >> 6;   // 8 waves; wave owns cols [16wv, 16wv+16)
  const int l15 = lane & 15, l4 = lane >> 4;
  const int col = wv*16 + l15;

  // ---- accumulators: 8 A-groups x 1 col-fragment each ----
  f32x4 acc1[8];
  {
    const float bv = b1[col];
    #pragma unroll
    for (int a = 0; a < 8; ++a){
      #pragma unroll
      for (int r = 0; r < 4; ++r) acc1[a][r] = bv;
    }
  }
  f32x4 acc2[8];

  const int kbase[5]  = { 0, 128, 384, 512, 256 };
  const int nchunk[5] = { 4, 4, 4, 1, 4 };

  for (int s = 0; s < 5; ++s){
    __syncthreads();                          // previous slab consumed / phase-1 ready
    // ---- stage slab s into fbuf ----
    if (s == 0 || s == 1 || s == 4){
      const float* F = (s == 0) ? xfi : (s == 1) ? xfj : ef;
      #pragma unroll
      for (int i = 0; i < 8; ++i){            // 128x32 float4 / 512 thr
        const int idx = i*512 + tid;
        const int e = idx >> 5, c4 = (idx & 31) << 2;
        long rr = base + e; if (rr >= E) rr = E-1;
        const float4 v = *reinterpret_cast<const float4*>(F + (size_t)rr*128 + c4);
        unsigned short* dst = &fbuf[e][c4];
        dst[0]=f2bf(v.x); dst[1]=f2bf(v.y); dst[2]=f2bf(v.z); dst[3]=f2bf(v.w);
      }
    } else if (s == 2){
      #pragma unroll
      for (int i = 0; i < 32; ++i){           // 128x128 / 512 thr
        const int idx = i*512 + tid;
        const int e = idx >> 7, c = idx & 127;
        const float v = (c < 7) ? terr_s[e][c] : u[(size_t)ibat_s[e]*128 + (c-7)];
        fbuf[e][c] = f2bf(v);
      }
    } else { // s == 3: k = 512..543 -> u[121..127] then zeros
      #pragma unroll
      for (int i = 0; i < 8; ++i){            // 128x32 / 512 thr
        const int idx = i*512 + tid;
        const int e = idx >> 5, c = idx & 31;
        const float v = (c < 7) ? u[(size_t)ibat_s[e]*128 + 121 + c] : 0.f;
        fbuf[e][c] = f2bf(v);
      }
    }
    __syncthreads();

    // ---- acc2 init right after ef slab staged (tight L2-hot re-read, fp32) ----
    if (s == 4){
      const float bv2 = b2[col];
      #pragma unroll
      for (int a = 0; a < 8; ++a){
        #pragma unroll
        for (int r = 0; r < 4; ++r){
          long orow = base + a*16 + l4*4 + r;
          if (orow >= E) orow = E-1;
          acc2[a][r] = ef[(size_t)orow*128 + col] + bv2;
        }
      }
    }

    // ---- MFMA chunks of this slab (B in-flight from fp32 W1, green pattern) ----
    for (int kc = 0; kc < nchunk[s]; ++kc){
      const int kl = kc*32 + l4*8;
      union { bf16x8 v; unsigned short us[8]; } B;
      #pragma unroll
      for (int j = 0; j < 8; ++j){
        const int kk = kbase[s] + kl + j;
        B.us[j] = (kk < 519) ? f2bf(W1[(size_t)kk*128 + col]) : (unsigned short)0;
      }
      #pragma unroll
      for (int a = 0; a < 8; ++a){
        const bf16x8 afr = *reinterpret_cast<const bf16x8*>(&fbuf[a*16 + l15][kl]);
        acc1[a] = __builtin_amdgcn_mfma_f32_16x16x32_bf16(afr, B.v, acc1[a], 0, 0, 0);
      }
    }
  }
  __syncthreads();   // ef slab consumed; fbuf free for h

  // ---- h = relu -> bf16 into fbuf; C/D: col, edge row = a*16 + l4*4 + r ----
  #pragma unroll
  for (int a = 0; a < 8; ++a){
    #pragma unroll
    for (int r = 0; r < 4; ++r)
      fbuf[a*16 + l4*4 + r][col] = f2bf(fmaxf(acc1[a][r], 0.f));
  }
  __syncthreads();

  // ---- GEMM2: acc2 += h @ W2 (A from LDS, B in-flight) ----
  #pragma unroll
  for (int ks = 0; ks < 4; ++ks){
    const int k0 = ks*32 + l4*8;
    union { bf16x8 v; unsigned short us[8]; } B;
    #pragma unroll
    for (int j = 0; j < 8; ++j)
      B.us[j] = f2bf(W2[(size_t)(k0 + j)*128 + col]);
    #pragma unroll
    for (int a = 0; a < 8; ++a){
      const bf16x8 afr = *reinterpret_cast<const bf16x8*>(&fbuf[a*16 + l15][k0]);
      acc2[a] = __builtin_amdgcn_mfma_f32_16x16x32_bf16(afr, B.v, acc2[a], 0, 0, 0);
    }
  }

  // ---- store edge_feat_out ----
  #pragma unroll
  for (int a = 0; a < 8; ++a){
    #pragma unroll
    for (int r = 0; r < 4; ++r){
      const long orow = base + a*16 + l4*4 + r;
      if (orow < E) outE[(size_t)orow*128 + col] = acc2[a][r];
    }
  }
}

extern "C" void kernel_launch(void* const* d_in, const int* in_sizes, int n_in,
                              void* d_out, int out_size, void* d_ws, size_t ws_size,
                              hipStream_t stream){
  const float* xfi  = (const float*)d_in[0];
  const float* xfj  = (const float*)d_in[1];
  const float* ef   = (const float*)d_in[2];
  const float* Ti   = (const float*)d_in[3];
  const float* Tj   = (const float*)d_in[4];
  const float* Th   = (const float*)d_in[5];
  const float* u    = (const float*)d_in[6];
  const int*   bat  = (const int*)d_in[7];
  const float* W1   = (const float*)d_in[8];
  const float* b1   = (const float*)d_in[9];
  const float* W2   = (const float*)d_in[10];
  const float* b2   = (const float*)d_in[11];
  const int E = in_sizes[0] / 128;

  float* outE = (float*)d_out;
  float* outT = outE + (size_t)E * 128;

  (void)d_ws; (void)ws_size;
  edge_k<<<(E + 127)/128, 512, 0, stream>>>(xfi, xfj, ef, Ti, Tj, Th, bat, u,
                                            W1, b1, W2, b2, outE, outT, E);
}

// Round 18
// 1065.786 us; speedup vs baseline: 1.8389x; 1.3122x over previous
//
#include <hip/hip_runtime.h>

typedef __attribute__((ext_vector_type(4))) float f32x4;
typedef __attribute__((ext_vector_type(8))) short bf16x8;

__device__ __forceinline__ unsigned short f2bf(float f){
  unsigned int x = __float_as_uint(f);
  return (unsigned short)((x + 0x7fffu + ((x >> 16) & 1u)) >> 16); // RNE
}

// ---------------- SE3 via explicit rotation matrices (fp32, exact) ----------------
struct Q  { float w,x,y,z; };
struct V3 { float x,y,z; };
struct M3 { float m[9]; };

__device__ __forceinline__ Q qmul(Q a, Q b){
  return { a.w*b.w - a.x*b.x - a.y*b.y - a.z*b.z,
           a.w*b.x + a.x*b.w + a.y*b.z - a.z*b.y,
           a.w*b.y - a.x*b.z + a.y*b.w + a.z*b.x,
           a.w*b.z + a.x*b.y - a.y*b.x + a.z*b.w };
}
__device__ __forceinline__ Q qconj(Q q){ return { q.w, -q.x, -q.y, -q.z }; }
__device__ __forceinline__ M3 q2R(Q q){
  const float w=q.w, x=q.x, y=q.y, z=q.z;
  M3 R;
  R.m[0]=1.f-2.f*(y*y+z*z); R.m[1]=2.f*(x*y-w*z);     R.m[2]=2.f*(x*z+w*y);
  R.m[3]=2.f*(x*y+w*z);     R.m[4]=1.f-2.f*(x*x+z*z); R.m[5]=2.f*(y*z-w*x);
  R.m[6]=2.f*(x*z-w*y);     R.m[7]=2.f*(y*z+w*x);     R.m[8]=1.f-2.f*(x*x+y*y);
  return R;
}
__device__ __forceinline__ V3 mv (M3 R, V3 v){
  return { R.m[0]*v.x + R.m[1]*v.y + R.m[2]*v.z,
           R.m[3]*v.x + R.m[4]*v.y + R.m[5]*v.z,
           R.m[6]*v.x + R.m[7]*v.y + R.m[8]*v.z };
}
__device__ __forceinline__ V3 mtv(M3 R, V3 v){
  return { R.m[0]*v.x + R.m[3]*v.y + R.m[6]*v.z,
           R.m[1]*v.x + R.m[4]*v.y + R.m[7]*v.z,
           R.m[2]*v.x + R.m[5]*v.y + R.m[8]*v.z };
}

// ---------------- single kernel: 64 edges/block, 4 waves (32 cols x 64 edges each) ----
// R14 geometry + slab-sequential tail through fbuf + h-in-fbuf overlay.
// Slab order (ef last): 0=xfi(k0=0) 1=xfj(k0=128) 2=tail128(k0=384) 3=tail32(k0=512) 4=ef(k0=256)
__global__ __launch_bounds__(256, 2) void edge_k(
    const float* __restrict__ xfi, const float* __restrict__ xfj, const float* __restrict__ ef,
    const float* __restrict__ Ti,  const float* __restrict__ Tj,  const float* __restrict__ Th,
    const int*   __restrict__ batch, const float* __restrict__ u,
    const float* __restrict__ W1,  const float* __restrict__ b1,
    const float* __restrict__ W2,  const float* __restrict__ b2,
    float* __restrict__ outE, float* __restrict__ outT, int E)
{
  __shared__ __align__(16) unsigned short fbuf[64][136];  // slab buffer, then h
  __shared__ float terr_s[64][8];
  __shared__ int   ibat_s[64];

  const int tid = threadIdx.x;              // 0..255 (4 waves)
  const long base = (long)blockIdx.x * 64;

  // ---- Phase 1: SE3 error (threads 0..63) + Tij_hat passthrough ----
  if (tid < 64){
    const long row = base + tid;
    const long rc  = row < E ? row : (long)(E-1);
    const float* pi = Ti + rc*7;
    const float* pj = Tj + rc*7;
    const float* ph = Th + rc*7;
    Q  qi{pi[0],pi[1],pi[2],pi[3]};  V3 tti{pi[4],pi[5],pi[6]};
    Q  qj{pj[0],pj[1],pj[2],pj[3]};  V3 ttj{pj[4],pj[5],pj[6]};
    Q  qh{ph[0],ph[1],ph[2],ph[3]};  V3 tth{ph[4],ph[5],ph[6]};
    M3 Ri = q2R(qi), Rj = q2R(qj), Rh = q2R(qh);
    V3 a  = mtv(Rj, ttj);
    V3 bv = mv(Ri, a);
    V3 c  { tti.x - bv.x, tti.y - bv.y, tti.z - bv.z };
    V3 d  = mv(Rh, c);
    Q  qe = qmul(qmul(qh, qi), qconj(qj));
    terr_s[tid][0] = qe.w;  terr_s[tid][1] = qe.x;
    terr_s[tid][2] = qe.y;  terr_s[tid][3] = qe.z;
    terr_s[tid][4] = tth.x + d.x;
    terr_s[tid][5] = tth.y + d.y;
    terr_s[tid][6] = tth.z + d.z;
    terr_s[tid][7] = 0.f;
    ibat_s[tid] = batch[rc];
    if (row < E){
      float* o = outT + row*7;
      o[0]=ph[0]; o[1]=ph[1]; o[2]=ph[2]; o[3]=ph[3];
      o[4]=ph[4]; o[5]=ph[5]; o[6]=ph[6];
    }
  }

  const int lane = tid & 63, wv = tid >> 6;   // 4 waves; wave owns cols [32wv, 32wv+32)
  const int l15 = lane & 15, l4 = lane >> 4;

  // ---- GEMM1 accumulators: 4 A-groups x 2 col-fragments (R14 geometry) ----
  f32x4 acc1[4][2];
  #pragma unroll
  for (int cf = 0; cf < 2; ++cf){
    const int col = wv*32 + cf*16 + l15;
    const float bv = b1[col];
    #pragma unroll
    for (int a = 0; a < 4; ++a){
      #pragma unroll
      for (int r = 0; r < 4; ++r) acc1[a][cf][r] = bv;
    }
  }

  const int kbase[5]  = { 0, 128, 384, 512, 256 };
  const int nchunk[5] = { 4, 4, 4, 1, 4 };

  for (int s = 0; s < 5; ++s){
    __syncthreads();                          // previous slab consumed / phase-1 ready
    // ---- stage slab s into fbuf ----
    if (s == 0 || s == 1 || s == 4){
      const float* F = (s == 0) ? xfi : (s == 1) ? xfj : ef;
      #pragma unroll
      for (int i = 0; i < 8; ++i){            // 64x32 float4 / 256 thr
        const int idx = i*256 + tid;
        const int e = idx >> 5, c4 = (idx & 31) << 2;
        long rr = base + e; if (rr >= E) rr = E-1;
        const float4 v = *reinterpret_cast<const float4*>(F + (size_t)rr*128 + c4);
        unsigned short* dst = &fbuf[e][c4];
        dst[0]=f2bf(v.x); dst[1]=f2bf(v.y); dst[2]=f2bf(v.z); dst[3]=f2bf(v.w);
      }
    } else if (s == 2){
      #pragma unroll
      for (int i = 0; i < 32; ++i){           // 64x128 / 256 thr
        const int idx = i*256 + tid;
        const int e = idx >> 7, c = idx & 127;
        const float v = (c < 7) ? terr_s[e][c] : u[(size_t)ibat_s[e]*128 + (c-7)];
        fbuf[e][c] = f2bf(v);
      }
    } else { // s == 3: k = 512..543 -> u[121..127] then zeros
      #pragma unroll
      for (int i = 0; i < 8; ++i){            // 64x32 / 256 thr
        const int idx = i*256 + tid;
        const int e = idx >> 5, c = idx & 31;
        const float v = (c < 7) ? u[(size_t)ibat_s[e]*128 + 121 + c] : 0.f;
        fbuf[e][c] = f2bf(v);
      }
    }
    __syncthreads();

    // ---- MFMA chunks of this slab (B in-flight from fp32 W1, green pattern) ----
    for (int kc = 0; kc < nchunk[s]; ++kc){
      const int kl = kc*32 + l4*8;
      bf16x8 afr[4];
      #pragma unroll
      for (int a = 0; a < 4; ++a)
        afr[a] = *reinterpret_cast<const bf16x8*>(&fbuf[a*16 + l15][kl]);
      #pragma unroll
      for (int cf = 0; cf < 2; ++cf){
        const int col = wv*32 + cf*16 + l15;
        union { bf16x8 v; unsigned short us[8]; } B;
        #pragma unroll
        for (int j = 0; j < 8; ++j){
          const int kk = kbase[s] + kl + j;
          B.us[j] = (kk < 519) ? f2bf(W1[(size_t)kk*128 + col]) : (unsigned short)0;
        }
        #pragma unroll
        for (int a = 0; a < 4; ++a)
          acc1[a][cf] = __builtin_amdgcn_mfma_f32_16x16x32_bf16(afr[a], B.v, acc1[a][cf], 0, 0, 0);
      }
    }
  }
  __syncthreads();   // ef slab consumed; fbuf free for h

  // ---- h = relu -> bf16 into fbuf; C/D: col=32wv+16cf+l15, edge row=a*16+l4*4+r ----
  #pragma unroll
  for (int a = 0; a < 4; ++a){
    #pragma unroll
    for (int cf = 0; cf < 2; ++cf){
      const int col = wv*32 + cf*16 + l15;
      #pragma unroll
      for (int r = 0; r < 4; ++r)
        fbuf[a*16 + l4*4 + r][col] = f2bf(fmaxf(acc1[a][cf][r], 0.f));
    }
  }
  __syncthreads();

  // ---- GEMM2: out = ef (fp32 global, late init — R14-proven) + b2 + h @ W2 ----
  f32x4 acc2[4][2];
  #pragma unroll
  for (int cf = 0; cf < 2; ++cf){
    const int col = wv*32 + cf*16 + l15;
    const float bv2 = b2[col];
    #pragma unroll
    for (int a = 0; a < 4; ++a){
      #pragma unroll
      for (int r = 0; r < 4; ++r){
        long orow = base + a*16 + l4*4 + r;
        if (orow >= E) orow = E-1;
        acc2[a][cf][r] = ef[(size_t)orow*128 + col] + bv2;
      }
    }
  }
  #pragma unroll
  for (int ks = 0; ks < 4; ++ks){
    const int k0 = ks*32 + l4*8;
    bf16x8 afr[4];
    #pragma unroll
    for (int a = 0; a < 4; ++a)
      afr[a] = *reinterpret_cast<const bf16x8*>(&fbuf[a*16 + l15][k0]);
    #pragma unroll
    for (int cf = 0; cf < 2; ++cf){
      const int col = wv*32 + cf*16 + l15;
      union { bf16x8 v; unsigned short us[8]; } B;
      #pragma unroll
      for (int j = 0; j < 8; ++j)
        B.us[j] = f2bf(W2[(size_t)(k0 + j)*128 + col]);
      #pragma unroll
      for (int a = 0; a < 4; ++a)
        acc2[a][cf] = __builtin_amdgcn_mfma_f32_16x16x32_bf16(afr[a], B.v, acc2[a][cf], 0, 0, 0);
    }
  }

  // ---- store edge_feat_out ----
  #pragma unroll
  for (int a = 0; a < 4; ++a){
    #pragma unroll
    for (int cf = 0; cf < 2; ++cf){
      const int col = wv*32 + cf*16 + l15;
      #pragma unroll
      for (int r = 0; r < 4; ++r){
        const long orow = base + a*16 + l4*4 + r;
        if (orow < E) outE[(size_t)orow*128 + col] = acc2[a][cf][r];
      }
    }
  }
}

extern "C" void kernel_launch(void* const* d_in, const int* in_sizes, int n_in,
                              void* d_out, int out_size, void* d_ws, size_t ws_size,
                              hipStream_t stream){
  const float* xfi  = (const float*)d_in[0];
  const float* xfj  = (const float*)d_in[1];
  const float* ef   = (const float*)d_in[2];
  const float* Ti   = (const float*)d_in[3];
  const float* Tj   = (const float*)d_in[4];
  const float* Th   = (const float*)d_in[5];
  const float* u    = (const float*)d_in[6];
  const int*   bat  = (const int*)d_in[7];
  const float* W1   = (const float*)d_in[8];
  const float* b1   = (const float*)d_in[9];
  const float* W2   = (const float*)d_in[10];
  const float* b2   = (const float*)d_in[11];
  const int E = in_sizes[0] / 128;

  float* outE = (float*)d_out;
  float* outT = outE + (size_t)E * 128;

  (void)d_ws; (void)ws_size;
  edge_k<<<(E + 63)/64, 256, 0, stream>>>(xfi, xfj, ef, Ti, Tj, Th, bat, u,
                                          W1, b1, W2, b2, outE, outT, E);
}

// Round 20
// 324.594 us; speedup vs baseline: 6.0379x; 3.2834x over previous
//
#include <hip/hip_runtime.h>

typedef __attribute__((ext_vector_type(4))) float f32x4;
typedef __attribute__((ext_vector_type(8))) short bf16x8;

__device__ __forceinline__ unsigned short f2bf(float f){
  unsigned int x = __float_as_uint(f);
  return (unsigned short)((x + 0x7fffu + ((x >> 16) & 1u)) >> 16); // RNE
}

// ---------------- SE3 via explicit rotation matrices (fp32, exact) ----------------
struct Q  { float w,x,y,z; };
struct V3 { float x,y,z; };
struct M3 { float m[9]; };

__device__ __forceinline__ Q qmul(Q a, Q b){
  return { a.w*b.w - a.x*b.x - a.y*b.y - a.z*b.z,
           a.w*b.x + a.x*b.w + a.y*b.z - a.z*b.y,
           a.w*b.y - a.x*b.z + a.y*b.w + a.z*b.x,
           a.w*b.z + a.x*b.y - a.y*b.x + a.z*b.w };
}
__device__ __forceinline__ Q qconj(Q q){ return { q.w, -q.x, -q.y, -q.z }; }
__device__ __forceinline__ M3 q2R(Q q){
  const float w=q.w, x=q.x, y=q.y, z=q.z;
  M3 R;
  R.m[0]=1.f-2.f*(y*y+z*z); R.m[1]=2.f*(x*y-w*z);     R.m[2]=2.f*(x*z+w*y);
  R.m[3]=2.f*(x*y+w*z);     R.m[4]=1.f-2.f*(x*x+z*z); R.m[5]=2.f*(y*z-w*x);
  R.m[6]=2.f*(x*z-w*y);     R.m[7]=2.f*(y*z+w*x);     R.m[8]=1.f-2.f*(x*x+y*y);
  return R;
}
__device__ __forceinline__ V3 mv (M3 R, V3 v){
  return { R.m[0]*v.x + R.m[1]*v.y + R.m[2]*v.z,
           R.m[3]*v.x + R.m[4]*v.y + R.m[5]*v.z,
           R.m[6]*v.x + R.m[7]*v.y + R.m[8]*v.z };
}
__device__ __forceinline__ V3 mtv(M3 R, V3 v){
  return { R.m[0]*v.x + R.m[3]*v.y + R.m[6]*v.z,
           R.m[1]*v.x + R.m[4]*v.y + R.m[7]*v.z,
           R.m[2]*v.x + R.m[5]*v.y + R.m[8]*v.z };
}

// ---------------- single kernel: 64 edges/block, 8 waves (16 cols x 64 edges each) ----
// R14 data paths and buffer structure EXACTLY (separate tailb/fbuf/hbf — h never
// overlays a read buffer, per R13/R19 law). Only the wave->work mapping changes:
// 8 waves x 16 cols doubles waves/CU to 16 (4/SIMD) at the same LDS.
__global__ __launch_bounds__(512) void edge_k(
    const float* __restrict__ xfi, const float* __restrict__ xfj, const float* __restrict__ ef,
    const float* __restrict__ Ti,  const float* __restrict__ Tj,  const float* __restrict__ Th,
    const int*   __restrict__ batch, const float* __restrict__ u,
    const float* __restrict__ W1,  const float* __restrict__ b1,
    const float* __restrict__ W2,  const float* __restrict__ b2,
    float* __restrict__ outE, float* __restrict__ outT, int E)
{
  __shared__ __align__(16) unsigned short tailb[64][168]; // k=384..543: Terr|u|pad
  __shared__ __align__(16) unsigned short fbuf[64][136];  // current 128-k feature slab
  __shared__ __align__(16) unsigned short hbf[64][136];   // h bf16 (dedicated)
  __shared__ int ibat_s[64];

  const int tid = threadIdx.x;              // 0..511 (8 waves)
  const long base = (long)blockIdx.x * 64;

  // ---- Phase 1: SE3 error (threads 0..63) + Tij_hat passthrough ----
  if (tid < 64){
    const long row = base + tid;
    const long rc  = row < E ? row : (long)(E-1);
    const float* pi = Ti + rc*7;
    const float* pj = Tj + rc*7;
    const float* ph = Th + rc*7;
    Q  qi{pi[0],pi[1],pi[2],pi[3]};  V3 tti{pi[4],pi[5],pi[6]};
    Q  qj{pj[0],pj[1],pj[2],pj[3]};  V3 ttj{pj[4],pj[5],pj[6]};
    Q  qh{ph[0],ph[1],ph[2],ph[3]};  V3 tth{ph[4],ph[5],ph[6]};
    M3 Ri = q2R(qi), Rj = q2R(qj), Rh = q2R(qh);
    V3 a  = mtv(Rj, ttj);
    V3 bv = mv(Ri, a);
    V3 c  { tti.x - bv.x, tti.y - bv.y, tti.z - bv.z };
    V3 d  = mv(Rh, c);
    Q  qe = qmul(qmul(qh, qi), qconj(qj));
    tailb[tid][0] = f2bf(qe.w);
    tailb[tid][1] = f2bf(qe.x);
    tailb[tid][2] = f2bf(qe.y);
    tailb[tid][3] = f2bf(qe.z);
    tailb[tid][4] = f2bf(tth.x + d.x);
    tailb[tid][5] = f2bf(tth.y + d.y);
    tailb[tid][6] = f2bf(tth.z + d.z);
    ibat_s[tid] = batch[rc];
    if (row < E){
      float* o = outT + row*7;
      o[0]=ph[0]; o[1]=ph[1]; o[2]=ph[2]; o[3]=ph[3];
      o[4]=ph[4]; o[5]=ph[5]; o[6]=ph[6];
    }
  }
  __syncthreads();

  // ---- stage u rows (cols 7..134) + zero pad (cols 135..167) ----
  for (int idx = tid; idx < 64*128; idx += 512){
    const int e = idx >> 7, c = idx & 127;
    tailb[e][7 + c] = f2bf(u[(size_t)ibat_s[e]*128 + c]);
  }
  for (int idx = tid; idx < 64*33; idx += 512){
    const int e = idx / 33, c = idx % 33;
    tailb[e][135 + c] = 0;
  }

  const int lane = tid & 63, wv = tid >> 6;   // 8 waves; wave owns cols [16wv, 16wv+16)
  const int l15 = lane & 15, l4 = lane >> 4;
  const int col = wv*16 + l15;

  // ---- GEMM1 accumulators: 4 A-groups x 1 col-fragment ----
  f32x4 acc1[4];
  {
    const float bv = b1[col];
    #pragma unroll
    for (int a = 0; a < 4; ++a){
      #pragma unroll
      for (int r = 0; r < 4; ++r) acc1[a][r] = bv;
    }
  }

  const float* fps[3] = { xfi, xfj, ef };
  for (int fb = 0; fb < 3; ++fb){
    const float* F = fps[fb];
    __syncthreads();                         // previous slab consumed
    // stage 64x128 feature slab (4 float4 per thread, coalesced)
    #pragma unroll
    for (int i = 0; i < 4; ++i){
      const int idx = i*512 + tid;
      const int e = idx >> 5, c4 = (idx & 31) << 2;
      long rr = base + e; if (rr >= E) rr = E-1;
      const float4 v = *reinterpret_cast<const float4*>(F + (size_t)rr*128 + c4);
      unsigned short* dst = &fbuf[e][c4];
      dst[0]=f2bf(v.x); dst[1]=f2bf(v.y); dst[2]=f2bf(v.z); dst[3]=f2bf(v.w);
    }
    __syncthreads();
    #pragma unroll
    for (int kc = 0; kc < 4; ++kc){
      const int kl = kc*32 + l4*8;
      bf16x8 afr[4];
      #pragma unroll
      for (int a = 0; a < 4; ++a)
        afr[a] = *reinterpret_cast<const bf16x8*>(&fbuf[a*16 + l15][kl]);
      union { bf16x8 v; unsigned short us[8]; } B;
      #pragma unroll
      for (int j = 0; j < 8; ++j){
        const int kk = fb*128 + kl + j;
        B.us[j] = f2bf(W1[(size_t)kk*128 + col]);
      }
      #pragma unroll
      for (int a = 0; a < 4; ++a)
        acc1[a] = __builtin_amdgcn_mfma_f32_16x16x32_bf16(afr[a], B.v, acc1[a], 0, 0, 0);
    }
  }
  // tail k-chunks (k = 384..543) from tailb; W zero-padded past 519
  #pragma unroll
  for (int tc = 0; tc < 5; ++tc){
    const int kt = tc*32 + l4*8;
    bf16x8 afr[4];
    #pragma unroll
    for (int a = 0; a < 4; ++a)
      afr[a] = *reinterpret_cast<const bf16x8*>(&tailb[a*16 + l15][kt]);
    union { bf16x8 v; unsigned short us[8]; } B;
    #pragma unroll
    for (int j = 0; j < 8; ++j){
      const int kk = 384 + kt + j;
      B.us[j] = (kk < 519) ? f2bf(W1[(size_t)kk*128 + col]) : (unsigned short)0;
    }
    #pragma unroll
    for (int a = 0; a < 4; ++a)
      acc1[a] = __builtin_amdgcn_mfma_f32_16x16x32_bf16(afr[a], B.v, acc1[a], 0, 0, 0);
  }

  // ---- h = relu -> bf16 into dedicated hbf; C/D: col, edge row = a*16+l4*4+r ----
  #pragma unroll
  for (int a = 0; a < 4; ++a){
    #pragma unroll
    for (int r = 0; r < 4; ++r)
      hbf[a*16 + l4*4 + r][col] = f2bf(fmaxf(acc1[a][r], 0.f));
  }
  __syncthreads();

  // ---- GEMM2: out = ef (fp32 global, R14-proven late init) + b2 + h @ W2 ----
  f32x4 acc2[4];
  {
    const float bv2 = b2[col];
    #pragma unroll
    for (int a = 0; a < 4; ++a){
      #pragma unroll
      for (int r = 0; r < 4; ++r){
        long orow = base + a*16 + l4*4 + r;
        if (orow >= E) orow = E-1;
        acc2[a][r] = ef[(size_t)orow*128 + col] + bv2;
      }
    }
  }
  #pragma unroll
  for (int ks = 0; ks < 4; ++ks){
    const int k0 = ks*32 + l4*8;
    bf16x8 afr[4];
    #pragma unroll
    for (int a = 0; a < 4; ++a)
      afr[a] = *reinterpret_cast<const bf16x8*>(&hbf[a*16 + l15][k0]);
    union { bf16x8 v; unsigned short us[8]; } B;
    #pragma unroll
    for (int j = 0; j < 8; ++j)
      B.us[j] = f2bf(W2[(size_t)(k0 + j)*128 + col]);
    #pragma unroll
    for (int a = 0; a < 4; ++a)
      acc2[a] = __builtin_amdgcn_mfma_f32_16x16x32_bf16(afr[a], B.v, acc2[a], 0, 0, 0);
  }

  // ---- store edge_feat_out ----
  #pragma unroll
  for (int a = 0; a < 4; ++a){
    #pragma unroll
    for (int r = 0; r < 4; ++r){
      const long orow = base + a*16 + l4*4 + r;
      if (orow < E) outE[(size_t)orow*128 + col] = acc2[a][r];
    }
  }
}

extern "C" void kernel_launch(void* const* d_in, const int* in_sizes, int n_in,
                              void* d_out, int out_size, void* d_ws, size_t ws_size,
                              hipStream_t stream){
  const float* xfi  = (const float*)d_in[0];
  const float* xfj  = (const float*)d_in[1];
  const float* ef   = (const float*)d_in[2];
  const float* Ti   = (const float*)d_in[3];
  const float* Tj   = (const float*)d_in[4];
  const float* Th   = (const float*)d_in[5];
  const float* u    = (const float*)d_in[6];
  const int*   bat  = (const int*)d_in[7];
  const float* W1   = (const float*)d_in[8];
  const float* b1   = (const float*)d_in[9];
  const float* W2   = (const float*)d_in[10];
  const float* b2   = (const float*)d_in[11];
  const int E = in_sizes[0] / 128;

  float* outE = (float*)d_out;
  float* outT = outE + (size_t)E * 128;

  (void)d_ws; (void)ws_size;
  edge_k<<<(E + 63)/64, 512, 0, stream>>>(xfi, xfj, ef, Ti, Tj, Th, bat, u,
                                          W1, b1, W2, b2, outE, outT, E);
}